// Round 17
// baseline (1134.919 us; speedup 1.0000x reference)
//
#include <hip/hip_runtime.h>
#include <hip/hip_bf16.h>
#include <stdint.h>

// Problem constants
#define B_    4
#define S_    4096
#define DIM_  2048
#define H_    16
#define HD_   128
#define M_    (B_ * S_)     // 16384 rows
#define K_    DIM_          // 2048
#define N_    (3 * DIM_)    // 6144 (q|k|v concatenated)

typedef __attribute__((ext_vector_type(8))) short bf16x8;
typedef __attribute__((ext_vector_type(4))) float f32x4;

// ---------------------------------------------------------------------------
// Kernel 1: X fp32 -> bf16
// ---------------------------------------------------------------------------
__global__ void cvt_x_kernel(const float* __restrict__ X,
                             __hip_bfloat16* __restrict__ Xb) {
    size_t i = ((size_t)blockIdx.x * 256 + threadIdx.x) * 8;
    float4 a = *reinterpret_cast<const float4*>(X + i);
    float4 b = *reinterpret_cast<const float4*>(X + i + 4);
    union { __hip_bfloat16 h[8]; uint4 u; } o;
    o.h[0] = __float2bfloat16(a.x);
    o.h[1] = __float2bfloat16(a.y);
    o.h[2] = __float2bfloat16(a.z);
    o.h[3] = __float2bfloat16(a.w);
    o.h[4] = __float2bfloat16(b.x);
    o.h[5] = __float2bfloat16(b.y);
    o.h[6] = __float2bfloat16(b.z);
    o.h[7] = __float2bfloat16(b.w);
    *reinterpret_cast<uint4*>(Xb + i) = o.u;
}

// ---------------------------------------------------------------------------
// Kernel 2: Wt[n][k] = W_sel[k][n] cast to bf16  (B^T layout)
// ---------------------------------------------------------------------------
__global__ void cvt_w_kernel(const float* __restrict__ Wq,
                             const float* __restrict__ Wk,
                             const float* __restrict__ Wv,
                             __hip_bfloat16* __restrict__ Wt) {
    __shared__ float tile[32][33];
    int w = blockIdx.z;
    const float* W = (w == 0) ? Wq : (w == 1) ? Wk : Wv;
    int n0 = blockIdx.x * 32;
    int k0 = blockIdx.y * 32;
    int tx = threadIdx.x, ty = threadIdx.y;
#pragma unroll
    for (int r = 0; r < 4; ++r) {
        int k = k0 + ty + r * 8;
        tile[ty + r * 8][tx] = W[(size_t)k * DIM_ + n0 + tx];
    }
    __syncthreads();
#pragma unroll
    for (int r = 0; r < 4; ++r) {
        int n = n0 + ty + r * 8;
        Wt[(size_t)(w * DIM_ + n) * K_ + k0 + tx] =
            __float2bfloat16(tile[tx][ty + r * 8]);
    }
}

// ---------------------------------------------------------------------------
// Kernel 3: 256x128 bf16 GEMM, BK=32, 4 waves of 128x64 (m201 wave shape).
// tau-law (R10/R13/R16 fit, k~12500us): tau = (1/WM+1/WN)+(1/BM+1/BN)
//   = 0.0352 here, -20% vs R10's 0.0437 -> predicted ~440us profiled.
// LDS dbuf 48 KB -> 3 blocks/CU; VGPR capped 170 (launch_bounds(256,3))
// -> 12 waves/CU. acc[8][4] (128 VGPR); A-frags read in two 4-group passes.
// Granule-XOR swizzle (0-conflict), XCD banding (6-wide tn band), nt stores,
// R10-proven schedule (stage t+1, vmcnt(0), barrier).
// ---------------------------------------------------------------------------
#define BM 256
#define BN 128
#define BK 32
#define NT (K_ / BK)    // 64

#define BAR()      __builtin_amdgcn_s_barrier()
#define WAIT_VM(n) asm volatile("s_waitcnt vmcnt(" #n ")")

__global__ __launch_bounds__(256, 3) void gemm_rope_kernel(
    const __hip_bfloat16* __restrict__ Xb,   // [M_][K_]
    const __hip_bfloat16* __restrict__ Wt,   // [N_][K_]
    const float* __restrict__ fcos,          // [S_][HD_]
    const float* __restrict__ fsin,          // [S_][HD_]
    float* __restrict__ out)                 // 3 regions of [M_][DIM_]
{
    __shared__ __hip_bfloat16 As[2][BM * BK];   // 2 x 16 KB
    __shared__ __hip_bfloat16 Bs[2][BN * BK];   // 2 x 8 KB

    // XCD L2-banding: 48 tn columns -> 6 per XCD (B band 6x128x2048x2B=3MB).
    int bid   = blockIdx.x;
    int x     = bid & 7;
    int local = bid >> 3;                    // 0..383
    int tn = x * 6 + local % 6;              // 0..47
    int tm = local / 6;                      // 0..63
    int m0 = tm * BM, n0 = tn * BN;

    int tid  = threadIdx.x;
    int lane = tid & 63;
    int w    = tid >> 6;                     // 0..3
    int wr   = w >> 1;                       // 0..1  (128-row half)
    int wc   = w & 1;                        // 0..1  (64-col half)

    // staging lane decomposition: 16 rows x 4 granules(16B) per gload
    int srow = lane >> 2;                    // 0..15
    int sgl  = lane & 3;                     // linear LDS granule
    int sgs  = (sgl ^ ((lane >> 3) & 3)) * 8;// pre-swizzled SOURCE elem offset
    int sgd  = sgl * 8;                      // linear LDS dest elem offset

    // fragment-read constants (granule-XOR swizzle; 0-conflict per R10)
    int fr = lane & 15;
    int fq = lane >> 4;                      // 0..3
    int fk = (fq ^ ((fr >> 1) & 3)) * 8;     // swizzled read granule offset

    // A: 256 rows = 16 gloads; wave w stages rows w*64 .. w*64+63 (4 ops)
#define STAGE_A(t, bb, r) do {                                                 \
        const __hip_bfloat16* _s = Xb + (size_t)(m0 + w * 64 + (r) * 16 + srow) * K_ \
                                      + (t) * BK + sgs;                        \
        __hip_bfloat16* _d = &As[bb][(w * 64 + (r) * 16 + srow) * BK + sgd];   \
        __builtin_amdgcn_global_load_lds(                                      \
            (const __attribute__((address_space(1))) void*)_s,                 \
            (__attribute__((address_space(3))) void*)_d, 16, 0, 0);            \
    } while (0)

    // B: 128 rows = 8 gloads; wave w stages rows w*32 .. w*32+31 (2 ops)
#define STAGE_B(t, bb, r) do {                                                 \
        const __hip_bfloat16* _s = Wt + (size_t)(n0 + w * 32 + (r) * 16 + srow) * K_ \
                                      + (t) * BK + sgs;                        \
        __hip_bfloat16* _d = &Bs[bb][(w * 32 + (r) * 16 + srow) * BK + sgd];   \
        __builtin_amdgcn_global_load_lds(                                      \
            (const __attribute__((address_space(1))) void*)_s,                 \
            (__attribute__((address_space(3))) void*)_d, 16, 0, 0);            \
    } while (0)

    f32x4  acc[8][4] = {};                   // 128x64 per wave (128 VGPR)
    bf16x8 a4[4], b[4];                      // 16 + 16 VGPR working set

#define LDB(bb) do {                                                           \
        _Pragma("unroll")                                                      \
        for (int j = 0; j < 4; ++j)                                            \
            b[j] = *reinterpret_cast<const bf16x8*>(                           \
                &Bs[bb][(wc * 64 + j * 16 + fr) * BK + fk]);                   \
    } while (0)

#define LDA4(bb, ih) do {                                                      \
        _Pragma("unroll")                                                      \
        for (int ii = 0; ii < 4; ++ii)                                         \
            a4[ii] = *reinterpret_cast<const bf16x8*>(                         \
                &As[bb][(wr * 128 + ((ih) * 4 + ii) * 16 + fr) * BK + fk]);    \
    } while (0)

#define MFMA_H(ih) do {                                                        \
        __builtin_amdgcn_s_setprio(1);                                         \
        _Pragma("unroll")                                                      \
        for (int ii = 0; ii < 4; ++ii)                                         \
        _Pragma("unroll")                                                      \
        for (int j = 0; j < 4; ++j)                                            \
            acc[(ih) * 4 + ii][j] = __builtin_amdgcn_mfma_f32_16x16x32_bf16(   \
                a4[ii], b[j], acc[(ih) * 4 + ii][j], 0, 0, 0);                 \
        __builtin_amdgcn_s_setprio(0);                                         \
    } while (0)

    // one K-tile: stage t+1 into Q; B frags once; A in two 4-group passes
#define TILE(t, P, Q) do {                                                     \
        if ((t) + 1 < NT) {                                                    \
            STAGE_A((t) + 1, Q, 0); STAGE_A((t) + 1, Q, 1);                    \
            STAGE_A((t) + 1, Q, 2); STAGE_A((t) + 1, Q, 3);                    \
            STAGE_B((t) + 1, Q, 0); STAGE_B((t) + 1, Q, 1);                    \
        }                                                                      \
        LDB(P);                                                                \
        LDA4(P, 0);                                                            \
        MFMA_H(0);                                                             \
        LDA4(P, 1);                                                            \
        MFMA_H(1);                                                             \
        WAIT_VM(0);                                                            \
        BAR();                                                                 \
    } while (0)

    // -------- prologue ------------------------------------------------------
    STAGE_A(0, 0, 0); STAGE_A(0, 0, 1); STAGE_A(0, 0, 2); STAGE_A(0, 0, 3);
    STAGE_B(0, 0, 0); STAGE_B(0, 0, 1);
    WAIT_VM(0);
    BAR();

    // -------- main loop: 64 K-tiles, 2 per unrolled iter --------------------
    for (int u = 0; u < NT / 2; ++u) {
        TILE(2 * u, 0, 1);
        TILE(2 * u + 1, 1, 0);
    }

    // -------- epilogue: RoPE + nontemporal store ----------------------------
    // C/D layout (16x16): col = lane&15 (=fr), row = (lane>>4)*4 + r
#pragma unroll
    for (int i = 0; i < 8; ++i) {
        int mbase = m0 + wr * 128 + i * 16 + fq * 4;
#pragma unroll
        for (int j = 0; j < 4; ++j) {
            int n = n0 + wc * 64 + j * 16 + fr;
            int region = n >> 11;            // 0=q,1=k,2=v
            int cc = n & (DIM_ - 1);
            int d  = cc & (HD_ - 1);
#pragma unroll
            for (int r = 0; r < 4; ++r) {
                int m = mbase + r;
                int s = m & (S_ - 1);
                float g  = acc[i][j][r];
                float gp = __shfl_xor(g, 1, 64);  // interleaved pair partner
                float o;
                if (region < 2) {
                    float cv = fcos[s * HD_ + d];
                    float sv = fsin[s * HD_ + d];
                    o = g * cv + ((cc & 1) ? gp * sv : -gp * sv);
                } else {
                    o = g;
                }
                __builtin_nontemporal_store(
                    o, &out[(size_t)region * M_ * DIM_ + (size_t)m * DIM_ + cc]);
            }
        }
    }
#undef STAGE_A
#undef STAGE_B
#undef LDB
#undef LDA4
#undef MFMA_H
#undef TILE
}

// ---------------------------------------------------------------------------
extern "C" void kernel_launch(void* const* d_in, const int* in_sizes, int n_in,
                              void* d_out, int out_size, void* d_ws, size_t ws_size,
                              hipStream_t stream) {
    const float* X    = (const float*)d_in[0];
    const float* fcos = (const float*)d_in[1];
    const float* fsin = (const float*)d_in[2];
    // d_in[3] = attention_mask (all ones, unused by the reference math)
    const float* Wq   = (const float*)d_in[4];
    const float* Wk   = (const float*)d_in[5];
    const float* Wv   = (const float*)d_in[6];
    float* out = (float*)d_out;

    __hip_bfloat16* Xb  = (__hip_bfloat16*)d_ws;
    __hip_bfloat16* Wtp = Xb + (size_t)M_ * K_;

    {
        int threads = 256;
        int blocks = (M_ * K_) / (threads * 8);   // 16384
        cvt_x_kernel<<<blocks, threads, 0, stream>>>(X, Xb);
    }
    {
        dim3 grid(DIM_ / 32, DIM_ / 32, 3);
        dim3 block(32, 8);
        cvt_w_kernel<<<grid, block, 0, stream>>>(Wq, Wk, Wv, Wtp);
    }
    {
        int blocks = (M_ / BM) * (N_ / BN);       // 64 * 48 = 3072
        gemm_rope_kernel<<<blocks, 256, 0, stream>>>(Xb, Wtp, fcos, fsin, out);
    }
}

// Round 18
// 523.682 us; speedup vs baseline: 2.1672x; 2.1672x over previous
//
#include <hip/hip_runtime.h>
#include <hip/hip_bf16.h>
#include <stdint.h>

// Problem constants
#define B_    4
#define S_    4096
#define DIM_  2048
#define H_    16
#define HD_   128
#define M_    (B_ * S_)     // 16384 rows
#define K_    DIM_          // 2048
#define N_    (3 * DIM_)    // 6144 (q|k|v concatenated)

typedef __attribute__((ext_vector_type(8))) short bf16x8;
typedef __attribute__((ext_vector_type(4))) float f32x4;

// ---------------------------------------------------------------------------
// Kernel 1: X fp32 -> bf16
// ---------------------------------------------------------------------------
__global__ void cvt_x_kernel(const float* __restrict__ X,
                             __hip_bfloat16* __restrict__ Xb) {
    size_t i = ((size_t)blockIdx.x * 256 + threadIdx.x) * 8;
    float4 a = *reinterpret_cast<const float4*>(X + i);
    float4 b = *reinterpret_cast<const float4*>(X + i + 4);
    union { __hip_bfloat16 h[8]; uint4 u; } o;
    o.h[0] = __float2bfloat16(a.x);
    o.h[1] = __float2bfloat16(a.y);
    o.h[2] = __float2bfloat16(a.z);
    o.h[3] = __float2bfloat16(a.w);
    o.h[4] = __float2bfloat16(b.x);
    o.h[5] = __float2bfloat16(b.y);
    o.h[6] = __float2bfloat16(b.z);
    o.h[7] = __float2bfloat16(b.w);
    *reinterpret_cast<uint4*>(Xb + i) = o.u;
}

// ---------------------------------------------------------------------------
// Kernel 2: Wt[n][k] = W_sel[k][n] cast to bf16  (B^T layout)
// ---------------------------------------------------------------------------
__global__ void cvt_w_kernel(const float* __restrict__ Wq,
                             const float* __restrict__ Wk,
                             const float* __restrict__ Wv,
                             __hip_bfloat16* __restrict__ Wt) {
    __shared__ float tile[32][33];
    int w = blockIdx.z;
    const float* W = (w == 0) ? Wq : (w == 1) ? Wk : Wv;
    int n0 = blockIdx.x * 32;
    int k0 = blockIdx.y * 32;
    int tx = threadIdx.x, ty = threadIdx.y;
#pragma unroll
    for (int r = 0; r < 4; ++r) {
        int k = k0 + ty + r * 8;
        tile[ty + r * 8][tx] = W[(size_t)k * DIM_ + n0 + tx];
    }
    __syncthreads();
#pragma unroll
    for (int r = 0; r < 4; ++r) {
        int n = n0 + ty + r * 8;
        Wt[(size_t)(w * DIM_ + n) * K_ + k0 + tx] =
            __float2bfloat16(tile[tx][ty + r * 8]);
    }
}

// ---------------------------------------------------------------------------
// Kernel 3 (FINAL = R10, best of 18 measured configs): 128x256 bf16 GEMM,
// BK=32, dbuf LDS 48 KB -> 2 blocks/CU (16 waves/CU), 8 waves of 64x64.
//   - granule-XOR LDS swizzle: logical granule g of row r at LDS granule
//     g^((r>>1)&3); linear LDS dest + pre-swizzled global source + swizzled
//     read (rule 21) -> SQ_LDS_BANK_CONFLICT == 0 (R10-verified)
//   - XCD L2-banding: XCD x owns tn in [3x,3x+3) -> 3 MB B set L2-resident
//   - m97 schedule: stage t+1 early, vmcnt(0)+barrier per K-tile; cross-block
//     TLP (2 blocks/CU) covers the read->MFMA dependency chain
//   - fused interleaved-RoPE epilogue, nontemporal stores
// Measured: timed 522.9 us total, GEMM ~545 profiled, MfmaUtil 34,
// absmax 0.03125. Deviations tested and rejected: 256x256 8-phase (x6),
// 32x32x16 MFMA (conflicts), B-direct-to-reg (2x), 4 blocks/CU small tile,
// 32 waves/CU (tau up), 128x64 waves @256 threads (reg spill).
// ---------------------------------------------------------------------------
#define BM 128
#define BN 256
#define BK 32
#define NT (K_ / BK)    // 64

#define BAR()      asm volatile("s_barrier" ::: "memory")
#define WAIT_VM(n) asm volatile("s_waitcnt vmcnt(" #n ")" ::: "memory")

__global__ __launch_bounds__(512, 4) void gemm_rope_kernel(
    const __hip_bfloat16* __restrict__ Xb,   // [M_][K_]
    const __hip_bfloat16* __restrict__ Wt,   // [N_][K_]
    const float* __restrict__ fcos,          // [S_][HD_]
    const float* __restrict__ fsin,          // [S_][HD_]
    float* __restrict__ out)                 // 3 regions of [M_][DIM_]
{
    __shared__ __hip_bfloat16 As[2][BM * BK];   // 2 x 8 KB
    __shared__ __hip_bfloat16 Bs[2][BN * BK];   // 2 x 16 KB

    // XCD L2-banding: XCD x owns tn in [3x,3x+3) -> B set 3 MB, L2-resident.
    int bid   = blockIdx.x;
    int x     = bid & 7;
    int local = bid >> 3;                    // 0..383
    int tn = x * 3 + local % 3;              // 0..23
    int tm = local / 3;                      // 0..127
    int m0 = tm * BM, n0 = tn * BN;

    int tid  = threadIdx.x;
    int lane = tid & 63;
    int w    = tid >> 6;                     // 0..7
    int wr   = w >> 2;                       // 0..1  (64-row half)
    int wc   = w & 3;                        // 0..3  (64-col quarter)

    // staging lane decomposition: 16 rows x 4 granules(16B) per gload
    int srow = lane >> 2;                    // 0..15
    int sgl  = lane & 3;                     // linear LDS granule
    int sgs  = (sgl ^ ((lane >> 3) & 3)) * 8;// pre-swizzled SOURCE elem offset
    int sgd  = sgl * 8;                      // linear LDS dest elem offset

    // fragment-read constants
    int fr = lane & 15;
    int fq = lane >> 4;                      // 0..3
    int fk = (fq ^ ((fr >> 1) & 3)) * 8;     // swizzled read granule offset

#define STAGE_A(t, bb) do {                                                    \
        const __hip_bfloat16* _s = Xb + (size_t)(m0 + w * 16 + srow) * K_      \
                                      + (t) * BK + sgs;                        \
        __hip_bfloat16* _d = &As[bb][(w * 16 + srow) * BK + sgd];              \
        __builtin_amdgcn_global_load_lds(                                      \
            (const __attribute__((address_space(1))) void*)_s,                 \
            (__attribute__((address_space(3))) void*)_d, 16, 0, 0);            \
    } while (0)

#define STAGE_B(t, bb, r) do {                                                 \
        const __hip_bfloat16* _s = Wt + (size_t)(n0 + w * 32 + (r) * 16 + srow) * K_ \
                                      + (t) * BK + sgs;                        \
        __hip_bfloat16* _d = &Bs[bb][(w * 32 + (r) * 16 + srow) * BK + sgd];   \
        __builtin_amdgcn_global_load_lds(                                      \
            (const __attribute__((address_space(1))) void*)_s,                 \
            (__attribute__((address_space(3))) void*)_d, 16, 0, 0);            \
    } while (0)

    f32x4  acc[4][4] = {};                   // 64x64 per wave
    bf16x8 a[4], b[4];

#define LDA(bb) do {                                                           \
        _Pragma("unroll")                                                      \
        for (int i = 0; i < 4; ++i)                                            \
            a[i] = *reinterpret_cast<const bf16x8*>(                           \
                &As[bb][(wr * 64 + i * 16 + fr) * BK + fk]);                   \
    } while (0)

#define LDB(bb) do {                                                           \
        _Pragma("unroll")                                                      \
        for (int j = 0; j < 4; ++j)                                            \
            b[j] = *reinterpret_cast<const bf16x8*>(                           \
                &Bs[bb][(wc * 64 + j * 16 + fr) * BK + fk]);                   \
    } while (0)

#define MFMA16() do {                                                          \
        __builtin_amdgcn_s_setprio(1);                                         \
        _Pragma("unroll")                                                      \
        for (int i = 0; i < 4; ++i)                                            \
        _Pragma("unroll")                                                      \
        for (int j = 0; j < 4; ++j)                                            \
            acc[i][j] = __builtin_amdgcn_mfma_f32_16x16x32_bf16(               \
                a[i], b[j], acc[i][j], 0, 0, 0);                               \
        __builtin_amdgcn_s_setprio(0);                                         \
    } while (0)

    // one K-tile: read buf P, stage t+1 into Q (m97 hazard pattern)
#define TILE(t, P, Q) do {                                                     \
        if ((t) + 1 < NT) {                                                    \
            STAGE_A((t) + 1, Q);                                               \
            STAGE_B((t) + 1, Q, 0); STAGE_B((t) + 1, Q, 1);                    \
        }                                                                      \
        LDA(P); LDB(P);                                                        \
        MFMA16();                                                              \
        WAIT_VM(0);                                                            \
        BAR();                                                                 \
    } while (0)

    // -------- prologue ------------------------------------------------------
    STAGE_A(0, 0);
    STAGE_B(0, 0, 0); STAGE_B(0, 0, 1);
    WAIT_VM(0);
    BAR();

    // -------- main loop: 64 K-tiles, 2 per unrolled iter --------------------
    for (int u = 0; u < NT / 2; ++u) {
        TILE(2 * u, 0, 1);
        TILE(2 * u + 1, 1, 0);
    }

    // -------- epilogue: RoPE + nontemporal store ----------------------------
    // C/D layout (16x16): col = lane&15 (=fr), row = (lane>>4)*4 + r
#pragma unroll
    for (int i = 0; i < 4; ++i) {
        int mbase = m0 + wr * 64 + i * 16 + fq * 4;
#pragma unroll
        for (int j = 0; j < 4; ++j) {
            int n = n0 + wc * 64 + j * 16 + fr;
            int region = n >> 11;            // 0=q,1=k,2=v
            int cc = n & (DIM_ - 1);
            int d  = cc & (HD_ - 1);
#pragma unroll
            for (int r = 0; r < 4; ++r) {
                int m = mbase + r;
                int s = m & (S_ - 1);
                float g  = acc[i][j][r];
                float gp = __shfl_xor(g, 1, 64);  // interleaved pair partner
                float o;
                if (region < 2) {
                    float cv = fcos[s * HD_ + d];
                    float sv = fsin[s * HD_ + d];
                    o = g * cv + ((cc & 1) ? gp * sv : -gp * sv);
                } else {
                    o = g;
                }
                __builtin_nontemporal_store(
                    o, &out[(size_t)region * M_ * DIM_ + (size_t)m * DIM_ + cc]);
            }
        }
    }
#undef STAGE_A
#undef STAGE_B
#undef LDA
#undef LDB
#undef MFMA16
#undef TILE
}

// ---------------------------------------------------------------------------
extern "C" void kernel_launch(void* const* d_in, const int* in_sizes, int n_in,
                              void* d_out, int out_size, void* d_ws, size_t ws_size,
                              hipStream_t stream) {
    const float* X    = (const float*)d_in[0];
    const float* fcos = (const float*)d_in[1];
    const float* fsin = (const float*)d_in[2];
    // d_in[3] = attention_mask (all ones, unused by the reference math)
    const float* Wq   = (const float*)d_in[4];
    const float* Wk   = (const float*)d_in[5];
    const float* Wv   = (const float*)d_in[6];
    float* out = (float*)d_out;

    __hip_bfloat16* Xb  = (__hip_bfloat16*)d_ws;
    __hip_bfloat16* Wtp = Xb + (size_t)M_ * K_;

    {
        int threads = 256;
        int blocks = (M_ * K_) / (threads * 8);   // 16384
        cvt_x_kernel<<<blocks, threads, 0, stream>>>(X, Xb);
    }
    {
        dim3 grid(DIM_ / 32, DIM_ / 32, 3);
        dim3 block(32, 8);
        cvt_w_kernel<<<grid, block, 0, stream>>>(Wq, Wk, Wv, Wtp);
    }
    {
        int blocks = (M_ / BM) * (N_ / BN);       // 128 * 24 = 3072
        gemm_rope_kernel<<<blocks, 512, 0, stream>>>(Xb, Wtp, fcos, fsin, out);
    }
}